// Round 18
// baseline (479.929 us; speedup 1.0000x reference)
//
#include <hip/hip_runtime.h>

#define DD 1024

typedef int   i32x4  __attribute__((ext_vector_type(4)));
typedef int   i32x8  __attribute__((ext_vector_type(8)));
typedef float f32x16 __attribute__((ext_vector_type(16)));

__device__ __forceinline__ float sigm(float x) { return 1.0f / (1.0f + __expf(-x)); }
__device__ __forceinline__ float tanh_fast(float x) {
  float e = __expf(-2.0f * fabsf(x));
  float t = (1.0f - e) / (1.0f + e);
  return copysignf(t, x);
}
__device__ __forceinline__ void gload_lds16(const void* g, void* l) {
  __builtin_amdgcn_global_load_lds((const __attribute__((address_space(1))) void*)g,
                                   (__attribute__((address_space(3))) void*)l, 16, 0, 0);
}
__device__ __forceinline__ unsigned pk_fp8x4(float a, float b, float c, float d) {
  int u = __builtin_amdgcn_cvt_pk_fp8_f32(a, b, 0, false);
  u = __builtin_amdgcn_cvt_pk_fp8_f32(c, d, u, true);
  return (unsigned)u;
}

// Fragment image, BK=64: 8 KB per (128-row, 64-k) K-tile, LANE-LINEAR.
//   subtile = 32 rows x 64 kk = 2 KB; addr(r,gran) = sel(gran)*512 + (r&31)*16,
//   sel(g) = ((g&1)<<1)|(g>>1). full = blk*131072 + kt*8192 + rowgroup*2048 + ...
// A image: blk covers 128 rows (rowgroup = (r>>5)&3). B image: blk = db,
// rowgroup = gate (n_t = gate*32 + dgl). Per-lane frag piece: h*512 + l31*16.

// ---- one-time weight prep: tiled B image + bias[4][1024] ----
// g=0: Wih_r+Whh_r ; g=1: Wih_z+Whh_z ; g=2: Wih_n ; g=3: Whh_n
__global__ __launch_bounds__(256) void prep_weights(
    const float* __restrict__ Wih, const float* __restrict__ Whh,
    const float* __restrict__ bih, const float* __restrict__ bhh,
    unsigned char* __restrict__ Wcat8, float* __restrict__ bias) {
  int i = blockIdx.x * 256 + threadIdx.x;
  int g = i >> 18;
  int rem = i & 262143;
  int n = rem >> 8;
  int k4 = rem & 255;                       // k = 4*k4
  const float4* wih4 = reinterpret_cast<const float4*>(Wih);
  const float4* whh4 = reinterpret_cast<const float4*>(Whh);
  float4 v;
  if (g == 0) {
    size_t idx = (size_t)n * 256 + k4;
    float4 a = wih4[idx], b = whh4[idx];
    v = make_float4(a.x + b.x, a.y + b.y, a.z + b.z, a.w + b.w);
  } else if (g == 1) {
    size_t idx = (size_t)(DD + n) * 256 + k4;
    float4 a = wih4[idx], b = whh4[idx];
    v = make_float4(a.x + b.x, a.y + b.y, a.z + b.z, a.w + b.w);
  } else if (g == 2) {
    size_t idx = (size_t)(2 * DD + n) * 256 + k4;
    v = wih4[idx];
  } else {
    size_t idx = (size_t)(2 * DD + n) * 256 + k4;
    v = whh4[idx];
  }
  // scale x32 (exact) so weights leave e4m3 denormal zone; MX B-scale 2^-5 undoes it
  unsigned pkd = pk_fp8x4(v.x * 32.0f, v.y * 32.0f, v.z * 32.0f, v.w * 32.0f);

  int db   = n >> 5;
  int dgl  = n & 31;
  int kt   = k4 >> 4;
  int gran = (k4 >> 2) & 3;
  int sel  = ((gran & 1) << 1) | (gran >> 1);
  int klo  = (k4 & 3) * 4;
  size_t addr = (size_t)db * 131072 + (size_t)kt * 8192 + g * 2048 +
                sel * 512 + dgl * 16 + klo;
  *reinterpret_cast<unsigned*>(Wcat8 + addr) = pkd;

  if (i < 4 * DD) {
    int bg = i >> 10, bn = i & 1023;
    float bv;
    if (bg == 0)      bv = bih[bn] + bhh[bn];
    else if (bg == 1) bv = bih[DD + bn] + bhh[DD + bn];
    else if (bg == 2) bv = bih[2 * DD + bn];
    else              bv = bhh[2 * DD + bn];
    bias[i] = bv;
  }
}

// ---- per-iteration: error GEMV + fp8 cast of state into tiled A image ----
__global__ __launch_bounds__(256) void error_cast(
    const float* S, const float* __restrict__ We, const float* __restrict__ be,
    unsigned char* __restrict__ Sb8, float* __restrict__ err) {
  __shared__ float part[4];
  const int row = blockIdx.x;
  const int t = threadIdx.x;                // k = 4t
  float4 v = reinterpret_cast<const float4*>(S + (size_t)row * DD)[t];
  float4 w = reinterpret_cast<const float4*>(We)[t];
  float dot = v.x * w.x + v.y * w.y + v.z * w.z + v.w * w.w;

  int r    = row & 127;
  int kt   = t >> 4;
  int gran = (t >> 2) & 3;
  int sel  = ((gran & 1) << 1) | (gran >> 1);
  int klo  = (t & 3) * 4;
  size_t addr = (size_t)(row >> 7) * 131072 + (size_t)kt * 8192 +
                (r >> 5) * 2048 + sel * 512 + (r & 31) * 16 + klo;
  *reinterpret_cast<unsigned*>(Sb8 + addr) = pk_fp8x4(v.x, v.y, v.z, v.w);

#pragma unroll
  for (int off = 32; off > 0; off >>= 1) dot += __shfl_xor(dot, off);
  if ((t & 63) == 0) part[t >> 6] = dot;
  __syncthreads();
  if (t == 0) err[row] = sigm(part[0] + part[1] + part[2] + part[3] + be[0]);
}

// ---- fused 4-gate MX-fp8 GEMM + GRU epilogue: A direct-to-reg, B-only LDS ----
// Block 256M x 128N(4g x 32dg), BK=64, 16 K-tiles, 4 waves; wave = 64M x 128N
// = 8x mfma_scale_f32_32x32x64_f8f6f4 (2 M-frags x 4 gates), acc 128 VGPR.
// A frags load global->VGPR from the fragment image (lane-linear, 1 KB/load,
// L2-hit: 16 db-blocks share each A panel). LDS holds ONLY B: 2 slots x 8 KB.
// Ledger: tile-t gate vmcnt(2) certifies A(t) [1-tile flight] + B(t) [2-tile],
// leaves B(t+1) in flight; never drains mid-loop. Per-CU per K-tile: LDS
// 156 cyc vs MFMA 136 cyc -> ~87% structural ceiling (was 31% in R16).
__global__ __launch_bounds__(256, 2) void gru_fused_gemm(
    const unsigned char* __restrict__ Sb8,   // tiled A image
    const unsigned char* __restrict__ Wcat8, // tiled B image
    const float* __restrict__ bias,          // [4096]
    const float* __restrict__ err,           // [M]
    const float* Sf,                         // [M][1024] f32 h (may alias out)
    float* out, int M) {
  __shared__ alignas(16) unsigned char Bs[2 * 8192];   // 16 KB (B only)

  // two-level XCD decode: xcd owns 16db x 32mb, db fast
  const int bid = blockIdx.x;
  const int x = bid & 7;
  const int c = bid >> 3;                  // 0..511
  const int db = (x & 1) * 16 + (c & 15);  // 0..31
  const int mb = (x >> 1) * 32 + (c >> 4); // 0..127 (256 rows each)

  const int tid = threadIdx.x;
  const int w = tid >> 6;                  // 0..3 ; wave owns rows w*64..+63
  const int lane = tid & 63;
  const int l31 = lane & 31;
  const int h = lane >> 5;

  // B staging: wave w copies bytes [w*1024,+1KB) and [+4KB) of each 8KB B tile
  const unsigned char* sB0 = Wcat8 + (size_t)db * 131072 + (size_t)w * 1024 + lane * 16;
  unsigned char* const dB0 = Bs + w * 1024;

  // A direct: frag f (f=0,1) = rowgroup rg = 2w+f; image block = 2mb + (w>>1)
  const unsigned char* aptr[2];
#pragma unroll
  for (int f = 0; f < 2; ++f) {
    int rg = 2 * w + f;
    aptr[f] = Sb8 + (size_t)(2 * mb + (rg >> 2)) * 131072 +
              (rg & 3) * 2048 + h * 512 + l31 * 16;
  }
  const int bq = h * 512 + l31 * 16;       // + g*2048 per gate, +1024 second half

  f32x16 acc[2][4];
#pragma unroll
  for (int f = 0; f < 2; ++f)
#pragma unroll
    for (int g = 0; g < 4; ++g)
#pragma unroll
      for (int r = 0; r < 16; ++r) acc[f][g][r] = 0.0f;

  i32x8 aX[2], aY[2];

#define LOAD_A(T, DST)                                                         \
  {                                                                            \
    _Pragma("unroll")                                                          \
    for (int f = 0; f < 2; ++f) {                                              \
      const unsigned char* p = aptr[f] + (size_t)(T) * 8192;                   \
      i32x4 lo = *reinterpret_cast<const i32x4*>(p);                           \
      i32x4 hi = *reinterpret_cast<const i32x4*>(p + 1024);                    \
      DST[f] = __builtin_shufflevector(lo, hi, 0, 1, 2, 3, 4, 5, 6, 7);        \
    }                                                                          \
  }

  auto stageB = [&](int t) {
    const int slot = (t & 1) * 8192;
    const size_t koff = (size_t)t * 8192;
    gload_lds16(sB0 + koff, dB0 + slot);
    gload_lds16(sB0 + koff + 4096, dB0 + slot + 4096);
  };

  // prologue: A(0)->X, stage B(0), B(1)   [outstanding: A0(4), B0(2), B1(2)]
  LOAD_A(0, aX)
  stageB(0);
  stageB(1);

#pragma unroll
  for (int t = 0; t < 16; ++t) {
    // gate: A(t)+B(t) are the oldest; leaves B(t+1) (2 loads) in flight
    if (t < 15) asm volatile("s_waitcnt vmcnt(2)" ::: "memory");
    else        asm volatile("s_waitcnt vmcnt(0)" ::: "memory");
    __builtin_amdgcn_s_barrier();

    if (t <= 14) {                          // A(t+1) -> other buffer (1-tile flight)
      if ((t & 1) == 0) LOAD_A(t + 1, aY)
      else              LOAD_A(t + 1, aX)
    }

    const int sb = (t & 1) * 8192;
    i32x8 bf[4];
#pragma unroll
    for (int g = 0; g < 4; ++g) {
      i32x4 b0 = *reinterpret_cast<const i32x4*>(Bs + sb + g * 2048 + bq);
      i32x4 b1 = *reinterpret_cast<const i32x4*>(Bs + sb + g * 2048 + bq + 1024);
      bf[g] = __builtin_shufflevector(b0, b1, 0, 1, 2, 3, 4, 5, 6, 7);
    }
    asm volatile("s_waitcnt lgkmcnt(0)" ::: "memory");
    __builtin_amdgcn_s_barrier();           // B slot sb free block-wide

    if (t <= 13) stageB(t + 2);             // into freed slot (2-tile flight)

    asm volatile("" ::: "memory");          // pin A loads before MFMA cluster
    __builtin_amdgcn_s_setprio(1);
    if ((t & 1) == 0) {
#pragma unroll
      for (int g = 0; g < 4; ++g)
#pragma unroll
        for (int f = 0; f < 2; ++f)
          acc[f][g] = __builtin_amdgcn_mfma_scale_f32_32x32x64_f8f6f4(
              aX[f], bf[g], acc[f][g], 0, 0, 0, 127, 0, 122);
    } else {
#pragma unroll
      for (int g = 0; g < 4; ++g)
#pragma unroll
        for (int f = 0; f < 2; ++f)
          acc[f][g] = __builtin_amdgcn_mfma_scale_f32_32x32x64_f8f6f4(
              aY[f], bf[g], acc[f][g], 0, 0, 0, 127, 0, 122);
    }
    __builtin_amdgcn_s_setprio(0);
  }
#undef LOAD_A

  // ---- epilogue: r,z,n + out = h + e*(1-z)*(n-h)
  // C/D 32x32 layout: col = lane&31, row = (reg&3) + 8*(reg>>2) + 4*(lane>>5)
  const int dgcol = db * 32 + l31;
  const float b_r = bias[dgcol];
  const float b_z = bias[DD + dgcol];
  const float b_i = bias[2 * DD + dgcol];
  const float b_h = bias[3 * DD + dgcol];
#pragma unroll
  for (int f = 0; f < 2; ++f) {
#pragma unroll
    for (int reg = 0; reg < 16; ++reg) {
      int rowf = (reg & 3) + 8 * (reg >> 2) + 4 * h;
      int m = mb * 256 + w * 64 + f * 32 + rowf;
      float e = err[m];
      float hh = Sf[(size_t)m * DD + dgcol];
      float r = sigm(acc[f][0][reg] + b_r);
      float z = sigm(acc[f][1][reg] + b_z);
      float n = tanh_fast(acc[f][2][reg] + b_i + r * (acc[f][3][reg] + b_h));
      out[(size_t)m * DD + dgcol] = hh + e * (1.0f - z) * (n - hh);
    }
  }
}

extern "C" void kernel_launch(void* const* d_in, const int* in_sizes, int n_in,
                              void* d_out, int out_size, void* d_ws, size_t ws_size,
                              hipStream_t stream) {
  const float* x   = (const float*)d_in[0];
  const float* Wih = (const float*)d_in[1];
  const float* Whh = (const float*)d_in[2];
  const float* bih = (const float*)d_in[3];
  const float* bhh = (const float*)d_in[4];
  const float* We  = (const float*)d_in[5];
  const float* be  = (const float*)d_in[6];
  float* out = (float*)d_out;
  const int M = in_sizes[0] / DD;   // 32768

  char* ws = (char*)d_ws;
  unsigned char* Sb8   = (unsigned char*)ws;                         // 32 MB (tiled)
  unsigned char* Wcat8 = (unsigned char*)(ws + (size_t)M * DD);      // 4 MB (tiled)
  float* bias = (float*)(ws + (size_t)M * DD + (size_t)4 * DD * DD);
  float* err  = (float*)(ws + (size_t)M * DD + (size_t)4 * DD * DD + (size_t)4 * DD * 4);

  prep_weights<<<4096, 256, 0, stream>>>(Wih, Whh, bih, bhh, Wcat8, bias);

  const int nwg = (M / 256) * 32;   // 4096
  const float* S = x;
  for (int it = 0; it < 2; ++it) {
    error_cast<<<M, 256, 0, stream>>>(S, We, be, Sb8, err);
    gru_fused_gemm<<<nwg, 256, 0, stream>>>(Sb8, Wcat8, bias, err, S, out, M);
    S = out;
  }
}

// Round 19
// 453.907 us; speedup vs baseline: 1.0573x; 1.0573x over previous
//
#include <hip/hip_runtime.h>

#define DD 1024

typedef int   i32x4  __attribute__((ext_vector_type(4)));
typedef int   i32x8  __attribute__((ext_vector_type(8)));
typedef float f32x16 __attribute__((ext_vector_type(16)));

__device__ __forceinline__ float sigm(float x) { return 1.0f / (1.0f + __expf(-x)); }
__device__ __forceinline__ float tanh_fast(float x) {
  float e = __expf(-2.0f * fabsf(x));
  float t = (1.0f - e) / (1.0f + e);
  return copysignf(t, x);
}
__device__ __forceinline__ void gload_lds16(const void* g, void* l) {
  __builtin_amdgcn_global_load_lds((const __attribute__((address_space(1))) void*)g,
                                   (__attribute__((address_space(3))) void*)l, 16, 0, 0);
}
__device__ __forceinline__ unsigned pk_fp8x4(float a, float b, float c, float d) {
  int u = __builtin_amdgcn_cvt_pk_fp8_f32(a, b, 0, false);
  u = __builtin_amdgcn_cvt_pk_fp8_f32(c, d, u, true);
  return (unsigned)u;
}

// Fragment image, BK=64: 8 KB per (128-row, 64-k) K-tile, LANE-LINEAR.
//   subtile = 32 rows x 64 kk = 2 KB; addr(r,gran) = sel(gran)*512 + (r&31)*16,
//   sel(g) = ((g&1)<<1)|(g>>1). full = blk*131072 + kt*8192 + rowgroup*2048 + ...
// A image: blk covers 128 rows (rowgroup = (r>>5)&3). B image: blk = db,
// rowgroup = gate (n_t = gate*32 + dgl). Per-lane frag piece: h*512 + l31*16.

// ---- one-time weight prep: tiled B image + bias[4][1024] ----
// g=0: Wih_r+Whh_r ; g=1: Wih_z+Whh_z ; g=2: Wih_n ; g=3: Whh_n
__global__ __launch_bounds__(256) void prep_weights(
    const float* __restrict__ Wih, const float* __restrict__ Whh,
    const float* __restrict__ bih, const float* __restrict__ bhh,
    unsigned char* __restrict__ Wcat8, float* __restrict__ bias) {
  int i = blockIdx.x * 256 + threadIdx.x;
  int g = i >> 18;
  int rem = i & 262143;
  int n = rem >> 8;
  int k4 = rem & 255;                       // k = 4*k4
  const float4* wih4 = reinterpret_cast<const float4*>(Wih);
  const float4* whh4 = reinterpret_cast<const float4*>(Whh);
  float4 v;
  if (g == 0) {
    size_t idx = (size_t)n * 256 + k4;
    float4 a = wih4[idx], b = whh4[idx];
    v = make_float4(a.x + b.x, a.y + b.y, a.z + b.z, a.w + b.w);
  } else if (g == 1) {
    size_t idx = (size_t)(DD + n) * 256 + k4;
    float4 a = wih4[idx], b = whh4[idx];
    v = make_float4(a.x + b.x, a.y + b.y, a.z + b.z, a.w + b.w);
  } else if (g == 2) {
    size_t idx = (size_t)(2 * DD + n) * 256 + k4;
    v = wih4[idx];
  } else {
    size_t idx = (size_t)(2 * DD + n) * 256 + k4;
    v = whh4[idx];
  }
  // scale x32 (exact) so weights leave e4m3 denormal zone; MX B-scale 2^-5 undoes it
  unsigned pkd = pk_fp8x4(v.x * 32.0f, v.y * 32.0f, v.z * 32.0f, v.w * 32.0f);

  int db   = n >> 5;
  int dgl  = n & 31;
  int kt   = k4 >> 4;
  int gran = (k4 >> 2) & 3;
  int sel  = ((gran & 1) << 1) | (gran >> 1);
  int klo  = (k4 & 3) * 4;
  size_t addr = (size_t)db * 131072 + (size_t)kt * 8192 + g * 2048 +
                sel * 512 + dgl * 16 + klo;
  *reinterpret_cast<unsigned*>(Wcat8 + addr) = pkd;

  if (i < 4 * DD) {
    int bg = i >> 10, bn = i & 1023;
    float bv;
    if (bg == 0)      bv = bih[bn] + bhh[bn];
    else if (bg == 1) bv = bih[DD + bn] + bhh[DD + bn];
    else if (bg == 2) bv = bih[2 * DD + bn];
    else              bv = bhh[2 * DD + bn];
    bias[i] = bv;
  }
}

// ---- per-iteration: error GEMV + fp8 cast of state into tiled A image ----
__global__ __launch_bounds__(256) void error_cast(
    const float* S, const float* __restrict__ We, const float* __restrict__ be,
    unsigned char* __restrict__ Sb8, float* __restrict__ err) {
  __shared__ float part[4];
  const int row = blockIdx.x;
  const int t = threadIdx.x;                // k = 4t
  float4 v = reinterpret_cast<const float4*>(S + (size_t)row * DD)[t];
  float4 w = reinterpret_cast<const float4*>(We)[t];
  float dot = v.x * w.x + v.y * w.y + v.z * w.z + v.w * w.w;

  int r    = row & 127;
  int kt   = t >> 4;
  int gran = (t >> 2) & 3;
  int sel  = ((gran & 1) << 1) | (gran >> 1);
  int klo  = (t & 3) * 4;
  size_t addr = (size_t)(row >> 7) * 131072 + (size_t)kt * 8192 +
                (r >> 5) * 2048 + sel * 512 + (r & 31) * 16 + klo;
  *reinterpret_cast<unsigned*>(Sb8 + addr) = pk_fp8x4(v.x, v.y, v.z, v.w);

#pragma unroll
  for (int off = 32; off > 0; off >>= 1) dot += __shfl_xor(dot, off);
  if ((t & 63) == 0) part[t >> 6] = dot;
  __syncthreads();
  if (t == 0) err[row] = sigm(part[0] + part[1] + part[2] + part[3] + be[0]);
}

// ---- fused 4-gate MX-fp8 GEMM + GRU epilogue ----
// Block 256M x 128N(4g x 32dg), BK=64, 16 K-tiles, 4 waves; wave = 64M x 128N
// = 8x mfma_scale_f32_32x32x64_f8f6f4 (2 M-frags x 4 gates), acc 128 VGPR.
// R16 schedule verbatim; only geometry changed. LDS/block-tile = 72 KB for 2x
// R16's output -> per-CU ceiling 49% MfmaUtil (was 31%). LDS 48 KB -> 3 blk/CU.
// Staging 6x1KB/wave/tile, gate vmcnt(6); B-frags read one-at-a-time in the
// MFMA loop to cap live VGPRs (~172 total, launch_bounds(256,3)).
__global__ __launch_bounds__(256, 3) void gru_fused_gemm(
    const unsigned char* __restrict__ Sb8,   // tiled A image
    const unsigned char* __restrict__ Wcat8, // tiled B image
    const float* __restrict__ bias,          // [4096]
    const float* __restrict__ err,           // [M]
    const float* Sf,                         // [M][1024] f32 h (may alias out)
    float* out, int M) {
  __shared__ alignas(16) unsigned char As[2 * 16384];   // 32 KB (2 slots)
  __shared__ alignas(16) unsigned char Bs[2 * 8192];    // 16 KB (2 slots)

  // two-level XCD decode: xcd owns 16db x 32mb, db fast
  const int bid = blockIdx.x;
  const int x = bid & 7;
  const int c = bid >> 3;                  // 0..511
  const int db = (x & 1) * 16 + (c & 15);  // 0..31
  const int mb = (x >> 1) * 32 + (c >> 4); // 0..127 (256 rows each)

  const int tid = threadIdx.x;
  const int w = tid >> 6;                  // 0..3 ; wave owns rows w*64..+63
  const int lane = tid & 63;
  const int l31 = lane & 31;
  const int h = lane >> 5;

  // staging: A = 16 chunks of 1KB (j = w+4i), image block 2mb + (j>=8); B as R16
  const unsigned char* srcA[4];
  unsigned char* dstA[4];
#pragma unroll
  for (int i = 0; i < 4; ++i) {
    int j = w + i * 4;                     // 0..15
    srcA[i] = Sb8 + (size_t)(2 * mb + (j >> 3)) * 131072 + (j & 7) * 1024 + lane * 16;
    dstA[i] = As + j * 1024;
  }
  const unsigned char* sB0 = Wcat8 + (size_t)db * 131072 + (size_t)w * 1024 + lane * 16;
  unsigned char* const dB0 = Bs + w * 1024;

  // frag read offsets: A rowgroup rg = 2w+f -> (rg>>2)*8192 + (rg&3)*2048 + ...
  int aoff[2];
#pragma unroll
  for (int f = 0; f < 2; ++f) {
    int rg = 2 * w + f;
    aoff[f] = (rg >> 2) * 8192 + (rg & 3) * 2048 + h * 512 + l31 * 16;
  }
  const int bq = h * 512 + l31 * 16;       // + g*2048 per gate, +1024 second half

  f32x16 acc[2][4];
#pragma unroll
  for (int f = 0; f < 2; ++f)
#pragma unroll
    for (int g = 0; g < 4; ++g)
#pragma unroll
      for (int r = 0; r < 16; ++r) acc[f][g][r] = 0.0f;

  auto stage = [&](int t) {
    const size_t koff = (size_t)t * 8192;
    const int sA = (t & 1) * 16384;
    const int sB = (t & 1) * 8192;
#pragma unroll
    for (int i = 0; i < 4; ++i) gload_lds16(srcA[i] + koff, dstA[i] + sA);
    gload_lds16(sB0 + koff, dB0 + sB);
    gload_lds16(sB0 + koff + 4096, dB0 + sB + 4096);
  };

  stage(0);
  stage(1);

#pragma unroll
  for (int t = 0; t < 16; ++t) {
    const int sA = (t & 1) * 16384;
    const int sB = (t & 1) * 8192;
    if (t < 15) asm volatile("s_waitcnt vmcnt(6)" ::: "memory");
    else        asm volatile("s_waitcnt vmcnt(0)" ::: "memory");
    __builtin_amdgcn_s_barrier();

    // A frags for this tile (fresh from LDS each tile; 16 VGPR live)
    i32x8 a[2];
#pragma unroll
    for (int f = 0; f < 2; ++f) {
      i32x4 a0 = *reinterpret_cast<const i32x4*>(As + sA + aoff[f]);
      i32x4 a1 = *reinterpret_cast<const i32x4*>(As + sA + aoff[f] + 1024);
      a[f] = __builtin_shufflevector(a0, a1, 0, 1, 2, 3, 4, 5, 6, 7);
    }

    __builtin_amdgcn_s_setprio(1);
#pragma unroll
    for (int g = 0; g < 4; ++g) {          // one B-frag live at a time
      i32x4 b0 = *reinterpret_cast<const i32x4*>(Bs + sB + g * 2048 + bq);
      i32x4 b1 = *reinterpret_cast<const i32x4*>(Bs + sB + g * 2048 + bq + 1024);
      i32x8 bf = __builtin_shufflevector(b0, b1, 0, 1, 2, 3, 4, 5, 6, 7);
      acc[0][g] = __builtin_amdgcn_mfma_scale_f32_32x32x64_f8f6f4(
          a[0], bf, acc[0][g], 0, 0, 0, 127, 0, 122);
      acc[1][g] = __builtin_amdgcn_mfma_scale_f32_32x32x64_f8f6f4(
          a[1], bf, acc[1][g], 0, 0, 0, 127, 0, 122);
    }
    __builtin_amdgcn_s_setprio(0);

    asm volatile("s_waitcnt lgkmcnt(0)" ::: "memory");
    __builtin_amdgcn_s_barrier();          // slots (t&1) fully consumed block-wide
    if (t <= 13) stage(t + 2);             // into freed slots
  }

  // ---- epilogue: r,z,n + out = h + e*(1-z)*(n-h)
  // C/D 32x32 layout: col = lane&31, row = (reg&3) + 8*(reg>>2) + 4*(lane>>5)
  const int dgcol = db * 32 + l31;
  const float b_r = bias[dgcol];
  const float b_z = bias[DD + dgcol];
  const float b_i = bias[2 * DD + dgcol];
  const float b_h = bias[3 * DD + dgcol];
#pragma unroll
  for (int f = 0; f < 2; ++f) {
#pragma unroll
    for (int reg = 0; reg < 16; ++reg) {
      int rowf = (reg & 3) + 8 * (reg >> 2) + 4 * h;
      int m = mb * 256 + w * 64 + f * 32 + rowf;
      float e = err[m];
      float hh = Sf[(size_t)m * DD + dgcol];
      float r = sigm(acc[f][0][reg] + b_r);
      float z = sigm(acc[f][1][reg] + b_z);
      float n = tanh_fast(acc[f][2][reg] + b_i + r * (acc[f][3][reg] + b_h));
      out[(size_t)m * DD + dgcol] = hh + e * (1.0f - z) * (n - hh);
    }
  }
}

extern "C" void kernel_launch(void* const* d_in, const int* in_sizes, int n_in,
                              void* d_out, int out_size, void* d_ws, size_t ws_size,
                              hipStream_t stream) {
  const float* x   = (const float*)d_in[0];
  const float* Wih = (const float*)d_in[1];
  const float* Whh = (const float*)d_in[2];
  const float* bih = (const float*)d_in[3];
  const float* bhh = (const float*)d_in[4];
  const float* We  = (const float*)d_in[5];
  const float* be  = (const float*)d_in[6];
  float* out = (float*)d_out;
  const int M = in_sizes[0] / DD;   // 32768

  char* ws = (char*)d_ws;
  unsigned char* Sb8   = (unsigned char*)ws;                         // 32 MB (tiled)
  unsigned char* Wcat8 = (unsigned char*)(ws + (size_t)M * DD);      // 4 MB (tiled)
  float* bias = (float*)(ws + (size_t)M * DD + (size_t)4 * DD * DD);
  float* err  = (float*)(ws + (size_t)M * DD + (size_t)4 * DD * DD + (size_t)4 * DD * 4);

  prep_weights<<<4096, 256, 0, stream>>>(Wih, Whh, bih, bhh, Wcat8, bias);

  const int nwg = (M / 256) * 32;   // 4096
  const float* S = x;
  for (int it = 0; it < 2; ++it) {
    error_cast<<<M, 256, 0, stream>>>(S, We, be, Sb8, err);
    gru_fused_gemm<<<nwg, 256, 0, stream>>>(Sb8, Wcat8, bias, err, S, out, M);
    S = out;
  }
}